// Round 9
// baseline (159.923 us; speedup 1.0000x reference)
//
#include <hip/hip_runtime.h>
#include <stdint.h>

// GradientLoss: sum_c mean( (conv3d_c(x) - conv3d_c(y))^2 ), c in {d,h,w} Sobel dirs.
// conv linear -> conv(x)-conv(y) = conv(x-y). Separable: s=[1,2,1], g=[1,0,-1];
// SAME zero pad; squared output -> flip irrelevant.
//
// R18: W-SPLIT — break the demand<->waves coupling. Discriminating experiment.
//  - R17 post-mortem: no spill (VGPR 188, WRITE 24KB), depth-2 (144 KB/CU in
//    flight) still 44us. Bytes-in-flight model dead.
//  - Two surviving models from R9..R17 counters:
//    (A) L2-miss drain ceiling: FETCH/dur = 1.7-1.85 TB/s in EVERY variant,
//        FETCH ~78 MB = unique(110) - L2(32) compulsory floor -> 43us pinned.
//    (B) demand-delivery ~ waves/CU: 12 waves -> 23 GB/s/CU (R13, ~= fill
//        kernel's 25.6), 6 waves -> 16-18 (R14/R17). All prior tilings moved
//        demand and waves TOGETHER, so demand/rate stayed ~44us.
//  - R18 holds 12 waves/CU at 202 MB demand: each 224-float row is split
//    across 2 waves (seg 0/1), 57 lanes x float2, 1-float seam overlap.
//    Lane 56 carries the seam pair so the shfl_up/down stencil is unchanged;
//    per-lane omask gives each output float exactly one owner.
//    RW=4 rows/wave, TD=10, depth-2 prefetch (R17 skeleton, float2 state).
//  - Pre-committed fork: ~34us confirms (B); ~44us confirms (A) and the next
//    call is ROOFLINE (compulsory L2-miss @ 1.8 TB/s).

#define N_  2
#define D_  160
#define H_  192
#define W_  224
#define PS  (H_ * W_)

#define TD  10                 // d-planes per block (160/10 = 16 chunks)
#define RW  4                  // output rows per wave
constexpr float SCALE = 1.0f / ((float)N_ * D_ * H_ * W_);

__device__ __forceinline__ float2 f2add(float2 a, float2 b) {
    return make_float2(a.x + b.x, a.y + b.y);
}
__device__ __forceinline__ float2 f2sub(float2 a, float2 b) {
    return make_float2(a.x - b.x, a.y - b.y);
}
__device__ __forceinline__ float2 f2fma(float k, float2 a, float2 b) {  // k*a + b
    return make_float2(fmaf(k, a.x, b.x), fmaf(k, a.y, b.y));
}

// ---- macros: buffer argument is a NAME (XRa/XRb); all indices static ----
#define LOADP(p, XR) do {                                                      \
    int pc_ = min(max((p), 0), D_ - 1);        /* clamp; masked via pm */      \
    const float* bx_ = vbx + (size_t)pc_ * PS;                                 \
    const float* by_ = vby + (size_t)pc_ * PS;                                 \
    _Pragma("unroll")                                                          \
    for (int r_ = 0; r_ < 6; ++r_) {                                           \
        XR[2 * r_]     = *(const float2*)(bx_ + off[r_]);                      \
        XR[2 * r_ + 1] = *(const float2*)(by_ + off[r_]);                      \
    }                                                                          \
} while (0)

#define BODY(ITV, XR) do {                                                     \
    const int it_ = (ITV);                                                     \
    const int q_ = d0 - 1 + it_;               /* plane consumed this iter */  \
    const float pm_ = (q_ >= 0 && q_ < D_) ? 1.f : 0.f;                        \
    float2 n0[RW], n1[RW], n2[RW];                                             \
    _Pragma("unroll")                                                          \
    for (int r_ = 0; r_ < 6; ++r_) {                                           \
        const float m_ = rmask[r_] * pm_;                                      \
        const float2 vv = make_float2((XR[2*r_].x - XR[2*r_+1].x) * m_,        \
                                      (XR[2*r_].y - XR[2*r_+1].y) * m_);       \
        float Lm = __shfl_up(vv.y, 1, 64);                                     \
        float Rp = __shfl_down(vv.x, 1, 64);                                   \
        if (lane == 0) Lm = 0.f;   /* seg0: w=-1 zero pad; seg1: masked out */ \
        /* seam: lane 56 holds real data -> lane 55's Rp correct; lanes>=57 */ \
        /* have vv=0 (lmask) -> seg1 lane 56's Rp = zero pad. */               \
        const float2 s_ = make_float2(Lm + 2.f * vv.x + vv.y,                  \
                                      vv.x + 2.f * vv.y + Rp);                 \
        const float2 g_ = make_float2(Lm - vv.y, vv.x - Rp);                   \
        _Pragma("unroll")                                                      \
        for (int j_ = 0; j_ < RW; ++j_) {                                      \
            if (r_ == j_) {                    /* top row of output j */       \
                n0[j_] = s_; n1[j_] = s_; n2[j_] = g_;                         \
            } else if (r_ == j_ + 1) {         /* center row, weight 2 */      \
                n0[j_] = f2fma(2.f, s_, n0[j_]);                               \
                n2[j_] = f2fma(2.f, g_, n2[j_]);                               \
            } else if (r_ == j_ + 2) {         /* bottom row */                \
                n0[j_] = f2add(n0[j_], s_);                                    \
                n1[j_] = f2sub(n1[j_], s_);                                    \
                n2[j_] = f2add(n2[j_], g_);                                    \
            }                                                                  \
        }                                                                      \
    }                                                                          \
    /* refill THIS buffer with plane d0+1+it (consumed at iter it+2) */        \
    if (it_ < TD) LOADP(d0 + 1 + it_, XR);                                     \
    /* d-combine for center plane q-1 (A = q-2, B = q-1, n = q) */             \
    if (it_ >= 2 && omask) {                                                   \
        _Pragma("unroll")                                                      \
        for (int j_ = 0; j_ < RW; ++j_) {                                      \
            const float2 gx = f2sub(A0[j_], n0[j_]);                           \
            const float2 gy = f2add(f2fma(2.f, B1[j_], A1[j_]), n1[j_]);       \
            const float2 gz = f2add(f2fma(2.f, B2[j_], A2[j_]), n2[j_]);       \
            acc = fmaf(gx.x, gx.x, acc); acc = fmaf(gx.y, gx.y, acc);          \
            acc = fmaf(gy.x, gy.x, acc); acc = fmaf(gy.y, gy.y, acc);          \
            acc = fmaf(gz.x, gz.x, acc); acc = fmaf(gz.y, gz.y, acc);          \
        }                                                                      \
    }                                                                          \
    /* rotate history */                                                       \
    _Pragma("unroll")                                                          \
    for (int j_ = 0; j_ < RW; ++j_) {                                          \
        A0[j_] = B0[j_]; A1[j_] = B1[j_]; A2[j_] = B2[j_];                     \
        B0[j_] = n0[j_]; B1[j_] = n1[j_]; B2[j_] = n2[j_];                     \
    }                                                                          \
} while (0)

__global__ __launch_bounds__(64, 1)
void grad_loss_kernel(const float* __restrict__ x, const float* __restrict__ y,
                      float* __restrict__ out) {
    const int lane = threadIdx.x;              // one wave per block

    const int seg = blockIdx.x;                // 0/1: W halves
    const int h0w = blockIdx.y * RW;           // this wave's first output row
    const int nchunks = D_ / TD;               // 16
    const int nb = blockIdx.z / nchunks;
    const int d0 = (blockIdx.z % nchunks) * TD;

    const float* vbx = x + (size_t)nb * ((size_t)D_ * PS);
    const float* vby = y + (size_t)nb * ((size_t)D_ * PS);

    // W mapping: seg0 lanes 0..56 load floats 2l (outputs 0..111 on lanes
    // 0..55; lane 56 = seam pair 112,113). seg1 lanes 0..56 load floats
    // 110+2l (outputs 112..223 on lanes 1..56; lane 0 = seam pair 110,111).
    const int lc = min(lane, 56);              // lanes 57..63 dup lane 56 addr
    const int base_w = (seg == 0) ? 2 * lc : 110 + 2 * lc;
    const float lmask = (lane <= 56) ? 1.f : 0.f;
    const bool omask = (seg == 0) ? (lane < 56) : (lane >= 1 && lane < 57);

    int off[6];
    float rmask[6];
    #pragma unroll
    for (int r = 0; r < 6; ++r) {              // loaded rows h0w-1 .. h0w+4
        int gh  = h0w - 1 + r;
        int ghc = min(max(gh, 0), H_ - 1);
        off[r]   = ghc * W_ + base_w;
        rmask[r] = (((unsigned)gh < (unsigned)H_)) ? lmask : 0.f;
    }

    float2 XRa[12], XRb[12];                   // 2 planes in flight: 6 rows x {x,y}

    float2 A0[RW], A1[RW], A2[RW], B0[RW], B1[RW], B2[RW];  // d-hist (q-2,q-1)
    const float2 z2 = make_float2(0.f, 0.f);
    #pragma unroll
    for (int j = 0; j < RW; ++j) { A0[j]=A1[j]=A2[j]=B0[j]=B1[j]=B2[j]=z2; }
    float acc = 0.f;

    // ---- prologue: planes d0-1, d0 in flight (2 batches) ----
    LOADP(d0 - 1, XRa);
    LOADP(d0,     XRb);

    // TD+2 = 12 iterations, manually unrolled x2 for static buffer selection
    #pragma unroll 1
    for (int i2 = 0; i2 < (TD + 2) / 2; ++i2) {
        BODY(2 * i2,     XRa);
        BODY(2 * i2 + 1, XRb);
    }

    // ---- reduction: wave butterfly, one atomic per wave ----
    #pragma unroll
    for (int off_ = 32; off_ > 0; off_ >>= 1)
        acc += __shfl_xor(acc, off_, 64);
    if (lane == 0) atomicAdd(out, acc * SCALE);
}

extern "C" void kernel_launch(void* const* d_in, const int* in_sizes, int n_in,
                              void* d_out, int out_size, void* d_ws, size_t ws_size,
                              hipStream_t stream) {
    const float* x = (const float*)d_in[0];
    const float* y = (const float*)d_in[1];
    float* out = (float*)d_out;

    hipMemsetAsync(out, 0, sizeof(float), stream);

    dim3 block(64);                     // 1 wave per block; no intra-loop sync
    dim3 grid(2,                        // W segments
              H_ / RW,                  // 48
              N_ * (D_ / TD));          // 32  -> 3072 waves = 12/CU
    grad_loss_kernel<<<grid, block, 0, stream>>>(x, y, out);
}